// Round 7
// baseline (628.218 us; speedup 1.0000x reference)
//
#include <hip/hip_runtime.h>

#define B_      128
#define C_IN_   256
#define NPTS    1024
#define C_OUT_  256
#define L_      3069
#define NTRIP   1023
#define T_OUT   1024
#define FEATS_SIZE (B_ * C_OUT_ * T_OUT)
#define KTOT    768

#define THREADS 512

typedef __attribute__((ext_vector_type(8))) short           bf16x8;
typedef __attribute__((ext_vector_type(8))) unsigned short  ushort8;
typedef __attribute__((ext_vector_type(4))) unsigned short  ushort4v;
typedef __attribute__((ext_vector_type(4))) float           f32x4;

__device__ __forceinline__ unsigned short f2bf(float f) {
    union { float f; unsigned u; } v; v.f = f;
    unsigned r = (v.u + 0x7FFFu + ((v.u >> 16) & 1u)) >> 16;   // RNE
    return (unsigned short)r;
}

__device__ __forceinline__ void gload16(const void* g, void* l) {
    __builtin_amdgcn_global_load_lds(
        (const __attribute__((address_space(1))) unsigned int*)g,
        (__attribute__((address_space(3))) unsigned int*)l, 16, 0, 0);
}

// ===================== TIER 2 (fast path) =====================
// K = 24 slices of 32 (slice s: tap t = s>>3, channel block cb = s&7).
// Block tile 256x256 (BN=256), 8 waves 4(m) x 2(n), wave tile 64x128.
// A slice image: 256 rows x 64 B (16 KB), slot-XOR (j ^ (r&3)), DOUBLE-buffered.
// B slice image: 256 rows x 64 B (16 KB), same swizzle, TRIPLE-buffered.
// LDS = 2*16 + 3*16 = 80 KB/block -> exactly 2 blocks/CU (160 KB).
// All fragment ds_read_b128 are full 1 KB permutations -> conflict-free.
// Stage = linear-dest global_load_lds; permutation lives in the SOURCE
// (convert_w4 for A, per-slot gather offset for B).
//
// Pipeline: body s = wait vmcnt(2) -> s_barrier -> ds_read frags(s) ->
//           issue A(s+1) [2 gload16] + B(s+2) [2 gload16] -> 32 MFMA.
// vmcnt(2): queue order ... A(s-1),B(s),A(s),B(s+1) -> needing A(s),B(s)
// done leaves only B(s+1)'s 2 ops outstanding. Body 23: vmcnt(0).
//
// ws: [0, 393216): wbf4 — weights bf16, slice-major pre-swizzled
//     [393216, +67108864): dataT — bf16 [b][n][c]
#define WOFF_T  0
#define DOFF_T  393216
#define WS_NEED_T2 (393216 + 67108864)

#define NSLICE  24
#define SLBYTES 16384
#define BBASE0  32768                  // B buffers at 32768 + (s%3)*16384
#define IDX6    65536                  // idx overlay in B-buf2 (prologue only)
#define SMEM6   81920
#define BN2     256

#define WAITV(n) asm volatile("s_waitcnt vmcnt(" #n ")" ::: "memory")

// weight fp32 -> bf16, slice-major fragment layout, slot-XOR pre-applied
__global__ __launch_bounds__(256) void convert_w4(
    const float* __restrict__ w, unsigned short* __restrict__ wbf4)
{
    int i = blockIdx.x * 256 + threadIdx.x;          // 0 .. 196607
    if (i >= C_OUT_ * KTOT) return;
    int e  = i & 7;
    int j  = (i >> 3) & 3;
    int r  = (i >> 5) & 255;
    int s  = i >> 13;           // 0..23
    int t  = s >> 3;
    int cb = s & 7;
    int lgp = j ^ (r & 3);
    int c  = cb * 32 + lgp * 8 + e;
    wbf4[i] = f2bf(w[r * KTOT + c * 3 + t]);
}

// data fp32 [b][c][n] -> dataT bf16 [b][n][c]
__global__ __launch_bounds__(256) void transpose_data(
    const float* __restrict__ data, unsigned short* __restrict__ dataT)
{
    __shared__ float T[64][68];
    const int bid = blockIdx.x;
    const int b   = bid >> 6;
    const int ct  = (bid & 63) >> 4;     // 0..3
    const int nt  = bid & 15;            // 0..15
    const int c0  = ct * 64, n0 = nt * 64;
    const int t   = threadIdx.x;
    const int row = t >> 2;              // 0..63
    const int q   = t & 3;

    const float* src = data + ((size_t)(b * C_IN_ + c0 + row)) * NPTS + n0 + q * 16;
    #pragma unroll
    for (int j = 0; j < 4; ++j) {
        float4 v = *(const float4*)(src + j * 4);
        *(float4*)&T[row][q * 16 + j * 4] = v;
    }
    __syncthreads();

    ushort8 o0, o1;
    #pragma unroll
    for (int j = 0; j < 8; ++j)  o0[j] = f2bf(T[q * 16 + j][row]);
    #pragma unroll
    for (int j = 0; j < 8; ++j)  o1[j] = f2bf(T[q * 16 + 8 + j][row]);
    unsigned short* dst = dataT + ((size_t)(b * NPTS) + n0 + row) * C_IN_ + c0 + q * 16;
    *(ushort8*)(dst)     = o0;
    *(ushort8*)(dst + 8) = o1;
}

// 8 waves as 4(m) x 2(n); per-wave output tile 64x128 (mi=4, ni=8).
__global__ __launch_bounds__(THREADS, 4) void treeconv_mfma6(
    const unsigned short* __restrict__ wbf4,
    const unsigned short* __restrict__ dataT,
    const int*   __restrict__ indexes,
    const float* __restrict__ bias,
    float*       __restrict__ out)
{
    __shared__ alignas(16) unsigned char smem[SMEM6];
    int* idx_s = (int*)(smem + IDX6);

    const int tid = threadIdx.x;
    // bijective XCD swizzle (512 = 8 XCD * 64); consecutive wg (same batch's
    // 4 n-tiles) land on the same XCD -> dataT L2 reuse.
    const int wg  = (blockIdx.x & 7) * 64 + (blockIdx.x >> 3);
    const int b   = wg >> 2;
    const int nt0 = (wg & 3) * BN2;

    {
        int off = nt0 * 3 + tid;
        idx_s[tid] = (off < L_) ? indexes[b * L_ + off] : 0;
        if (tid < BN2 * 3 - 512) {
            int off2 = nt0 * 3 + 512 + tid;
            idx_s[512 + tid] = (off2 < L_) ? indexes[b * L_ + off2] : 0;
        }
    }
    __syncthreads();

    const int lane = tid & 63;
    const int wid  = tid >> 6;
    const int wm   = wid >> 1;     // m base = wm*64
    const int wn   = wid & 1;      // n base = wn*128
    const int l15  = lane & 15;
    const int lg   = lane >> 4;

    // ---- B stage gather offsets: 2 slots/thread (tid, tid+512) ----
    // image (n = slot>>2, j = slot&3) holds channels for lgp = j ^ (n&3)
    unsigned bofa[3], bofb[3];
    {
        const int s0 = tid,        n0_ = s0 >> 2, lp0 = (s0 & 3) ^ (n0_ & 3);
        const int s1 = tid + 512,  n1_ = s1 >> 2, lp1 = (s1 & 3) ^ (n1_ & 3);
        #pragma unroll
        for (int t = 0; t < 3; ++t) {
            bofa[t] = (unsigned)(idx_s[n0_ * 3 + t] * 512 + lp0 * 16);
            bofb[t] = (unsigned)(idx_s[n1_ * 3 + t] * 512 + lp1 * 16);
        }
    }

    const char* dTb  = (const char*)dataT + (size_t)b * NPTS * C_IN_ * 2;
    const char* wsrc = (const char*)wbf4;
    const int   a0   = tid * 16;                    // A slot bytes (x2: +8192)
    const int   bd0  = tid * 16;                    // B slot bytes (x2: +8192)

    // fragment read bases (slot-XOR: r&3 == l15&3, lane-constant)
    const unsigned xsl   = (unsigned)((lg ^ (l15 & 3)) << 4);
    const unsigned abase = (unsigned)((wm * 64 + l15) * 64) + xsl;
    const unsigned bbase = (unsigned)(BBASE0 + (wn * 128 + l15) * 64) + xsl;

    f32x4 acc[4][8];
    #pragma unroll
    for (int mi = 0; mi < 4; ++mi)
        #pragma unroll
        for (int ni = 0; ni < 8; ++ni)
            acc[mi][ni] = (f32x4){0.f, 0.f, 0.f, 0.f};

#define ASTAGE(s) do {                                                        \
        gload16(wsrc + (s) * SLBYTES + a0,        smem + ((s) & 1) * SLBYTES + a0); \
        gload16(wsrc + (s) * SLBYTES + a0 + 8192, smem + ((s) & 1) * SLBYTES + a0 + 8192); \
    } while (0)
#define BSTAGE(s) do {                                                        \
        unsigned c_ = (unsigned)(((s) & 7) * 64);                             \
        unsigned b0_ = (((s) >> 3) == 0 ? bofa[0] : ((s) >> 3) == 1 ? bofa[1] : bofa[2]) + c_; \
        unsigned b1_ = (((s) >> 3) == 0 ? bofb[0] : ((s) >> 3) == 1 ? bofb[1] : bofb[2]) + c_; \
        gload16(dTb + b0_, smem + BBASE0 + ((s) % 3) * SLBYTES + bd0);        \
        gload16(dTb + b1_, smem + BBASE0 + ((s) % 3) * SLBYTES + bd0 + 8192); \
    } while (0)

    // prologue queue: A(0) A(0) B(0) B(0) B(1) B(1)
    ASTAGE(0);
    BSTAGE(0);
    BSTAGE(1);

    #pragma unroll
    for (int s = 0; s < NSLICE; ++s) {
        // need A(s),B(s) retired; only B(s+1) (2 ops) may stay in flight.
        if (s == NSLICE - 1) WAITV(0);
        else                 WAITV(2);
        __builtin_amdgcn_s_barrier();
        asm volatile("" ::: "memory");

        const unsigned char* ap = smem + (s & 1) * SLBYTES;
        const unsigned char* bp = smem + (s % 3) * SLBYTES;
        bf16x8 a[4], bb[8];
        #pragma unroll
        for (int mi = 0; mi < 4; ++mi)
            a[mi] = *(const bf16x8*)(ap + abase + mi * 1024);
        #pragma unroll
        for (int ni = 0; ni < 8; ++ni)
            bb[ni] = *(const bf16x8*)(bp + bbase + ni * 1024);

        // issue next stages; targets were freed by the barrier above:
        // A(s+1) -> A-buf (s+1)&1 (read in body s-1); B(s+2) -> B-buf
        // (s+2)%3 == (s-1)%3 (read in body s-1).
        if (s + 1 < NSLICE) ASTAGE(s + 1);
        if (s + 2 < NSLICE) BSTAGE(s + 2);

        #pragma unroll
        for (int mi = 0; mi < 4; ++mi)
            #pragma unroll
            for (int ni = 0; ni < 8; ++ni)
                acc[mi][ni] = __builtin_amdgcn_mfma_f32_16x16x32_bf16(
                    a[mi], bb[ni], acc[mi][ni], 0, 0, 0);
    }
#undef ASTAGE
#undef BSTAGE

    float* outB = out + (size_t)b * (C_OUT_ * T_OUT);
    #pragma unroll
    for (int mi = 0; mi < 4; ++mi) {
        #pragma unroll
        for (int r = 0; r < 4; ++r) {
            int o = wm * 64 + mi * 16 + lg * 4 + r;
            float bv = bias[o];
            #pragma unroll
            for (int ni = 0; ni < 8; ++ni) {
                int n = nt0 + wn * 128 + ni * 16 + l15;
                if (n < NTRIP)
                    outB[o * T_OUT + 1 + n] = acc[mi][ni][r] + bv;
            }
        }
    }
}

// ===================== TIER 1/0 (round-2 fallback) =====================
#define BN      64
#define BK      96
#define NCHUNK  8
#define AS_OFF  0
#define BS_OFF  49152
#define IDX_OFF 61440
#define SMEM_BYTES 62208

template<bool PREW>
__global__ __launch_bounds__(THREADS, 4) void treeconv_mfma(
    const float* __restrict__ data,
    const int*   __restrict__ indexes,
    const float* __restrict__ w32,
    const unsigned short* __restrict__ wbf,
    const float* __restrict__ bias,
    float*       __restrict__ out)
{
    __shared__ alignas(16) unsigned char smem[SMEM_BYTES];
    int* idx_s = (int*)(smem + IDX_OFF);

    const int tid = threadIdx.x;
    const int b   = blockIdx.x >> 4;
    const int nt0 = (blockIdx.x & 15) * BN;

    if (tid < BN * 3) {
        int off = nt0 * 3 + tid;
        idx_s[tid] = (off < L_) ? indexes[b * L_ + off] : 0;
    }
    __syncthreads();

    const int lane = tid & 63;
    const int wid  = tid >> 6;
    const int wm   = wid >> 1;
    const int wn   = wid & 1;
    const int l15  = lane & 15;
    const int lg   = lane >> 4;

    f32x4 acc[4][2];
    #pragma unroll
    for (int mi = 0; mi < 4; ++mi)
        #pragma unroll
        for (int ni = 0; ni < 2; ++ni)
            acc[mi][ni] = (f32x4){0.f, 0.f, 0.f, 0.f};

    const float* dataB = data + (size_t)b * (C_IN_ * NPTS);
    const int ar = tid >> 1;
    const int ah = tid & 1;
    const int gn = tid & 63;
    const int g8 = tid >> 6;

    for (int kc = 0; kc < NCHUNK; ++kc) {
        {
            const int ab = ar * 192 + ah * 96;
            const int sw = (ar & 7) << 4;
            if (PREW) {
                const ushort8* src = (const ushort8*)(wbf + ar * KTOT + kc * BK + ah * 48);
                #pragma unroll
                for (int j = 0; j < 6; ++j) {
                    ushort8 v = src[j];
                    *(ushort8*)(smem + ((ab + j * 16) ^ sw)) = v;
                }
            } else {
                const float* src = w32 + ar * KTOT + kc * BK + ah * 48;
                #pragma unroll
                for (int j = 0; j < 6; ++j) {
                    float4 fa = *(const float4*)(src + j * 8);
                    float4 fb = *(const float4*)(src + j * 8 + 4);
                    ushort8 v;
                    v[0] = f2bf(fa.x); v[1] = f2bf(fa.y); v[2] = f2bf(fa.z); v[3] = f2bf(fa.w);
                    v[4] = f2bf(fb.x); v[5] = f2bf(fb.y); v[6] = f2bf(fb.z); v[7] = f2bf(fb.w);
                    *(ushort8*)(smem + ((ab + j * 16) ^ sw)) = v;
                }
            }
        }
        {
            const int* ip = idx_s + gn * 3;
            int ix0 = ip[0], ix1 = ip[1], ix2 = ip[2];
            const float* dp = dataB + (kc * 32 + g8 * 4) * NPTS;
            unsigned short vals[12];
            #pragma unroll
            for (int ci = 0; ci < 4; ++ci) {
                vals[ci * 3 + 0] = f2bf(dp[ix0]);
                vals[ci * 3 + 1] = f2bf(dp[ix1]);
                vals[ci * 3 + 2] = f2bf(dp[ix2]);
                dp += NPTS;
            }
            const int bb = BS_OFF + gn * 192 + g8 * 24;
            const int sw = (gn & 7) << 4;
            #pragma unroll
            for (int q = 0; q < 3; ++q) {
                ushort4v v;
                v[0] = vals[q * 4 + 0]; v[1] = vals[q * 4 + 1];
                v[2] = vals[q * 4 + 2]; v[3] = vals[q * 4 + 3];
                *(ushort4v*)(smem + ((bb + q * 8) ^ sw)) = v;
            }
        }
        __syncthreads();

        #pragma unroll
        for (int ks = 0; ks < 3; ++ks) {
            bf16x8 a[4], bf[2];
            const int kb = ks * 64 + lg * 16;
            #pragma unroll
            for (int mi = 0; mi < 4; ++mi) {
                int row = wm * 64 + mi * 16 + l15;
                a[mi] = *(const bf16x8*)(smem + ((row * 192 + kb) ^ ((row & 7) << 4)));
            }
            #pragma unroll
            for (int ni = 0; ni < 2; ++ni) {
                int row = wn * 32 + ni * 16 + l15;
                bf[ni] = *(const bf16x8*)(smem + ((BS_OFF + row * 192 + kb) ^ ((row & 7) << 4)));
            }
            #pragma unroll
            for (int mi = 0; mi < 4; ++mi)
                #pragma unroll
                for (int ni = 0; ni < 2; ++ni)
                    acc[mi][ni] = __builtin_amdgcn_mfma_f32_16x16x32_bf16(
                        a[mi], bf[ni], acc[mi][ni], 0, 0, 0);
        }
        __syncthreads();
    }

    float* outB = out + (size_t)b * (C_OUT_ * T_OUT);
    #pragma unroll
    for (int mi = 0; mi < 4; ++mi) {
        #pragma unroll
        for (int r = 0; r < 4; ++r) {
            int o = wm * 64 + mi * 16 + lg * 4 + r;
            float bv = bias[o];
            #pragma unroll
            for (int ni = 0; ni < 2; ++ni) {
                int n = nt0 + wn * 32 + ni * 16 + l15;
                if (n < NTRIP)
                    outB[o * T_OUT + 1 + n] = acc[mi][ni][r] + bv;
            }
        }
    }
}

__global__ __launch_bounds__(256) void convert_w(
    const float* __restrict__ w, unsigned short* __restrict__ wbf)
{
    int i = (blockIdx.x * 256 + threadIdx.x) * 4;
    if (i < C_OUT_ * KTOT) {
        float4 f = *(const float4*)(w + i);
        ushort4v v;
        v[0] = f2bf(f.x); v[1] = f2bf(f.y); v[2] = f2bf(f.z); v[3] = f2bf(f.w);
        *(ushort4v*)(wbf + i) = v;
    }
}

__global__ __launch_bounds__(256) void aux_kernel(
    const int* __restrict__ indexes, float* __restrict__ out)
{
    int i = blockIdx.x * 256 + threadIdx.x;
    if (i < B_ * L_)
        out[FEATS_SIZE + i] = (float)indexes[i];
    if (i < B_ * C_OUT_)
        out[(size_t)i * T_OUT] = 0.0f;
}

extern "C" void kernel_launch(void* const* d_in, const int* in_sizes, int n_in,
                              void* d_out, int out_size, void* d_ws, size_t ws_size,
                              hipStream_t stream)
{
    const float* data    = (const float*)d_in[0];
    const int*   indexes = (const int*)d_in[1];
    const float* weight  = (const float*)d_in[2];
    const float* bias    = (const float*)d_in[3];
    float* out = (float*)d_out;

    hipLaunchKernelGGL(aux_kernel, dim3((B_ * L_ + 255) / 256), dim3(256), 0, stream,
                       indexes, out);

    if (ws_size >= (size_t)WS_NEED_T2) {
        unsigned short* wbf4  = (unsigned short*)((char*)d_ws + WOFF_T);
        unsigned short* dataT = (unsigned short*)((char*)d_ws + DOFF_T);
        hipLaunchKernelGGL(convert_w4, dim3((C_OUT_ * KTOT + 255) / 256), dim3(256),
                           0, stream, weight, wbf4);
        hipLaunchKernelGGL(transpose_data, dim3(B_ * 64), dim3(256), 0, stream,
                           data, dataT);
        hipLaunchKernelGGL(treeconv_mfma6, dim3(B_ * 4), dim3(THREADS), 0, stream,
                           wbf4, dataT, indexes, bias, out);
    } else if (ws_size >= (size_t)(C_OUT_ * KTOT * 2)) {
        unsigned short* wbf = (unsigned short*)d_ws;
        hipLaunchKernelGGL(convert_w, dim3((C_OUT_ * KTOT / 4 + 255) / 256), dim3(256),
                           0, stream, weight, wbf);
        hipLaunchKernelGGL((treeconv_mfma<true>), dim3(B_ * 16), dim3(THREADS), 0, stream,
                           data, indexes, weight, wbf, bias, out);
    } else {
        hipLaunchKernelGGL((treeconv_mfma<false>), dim3(B_ * 16), dim3(THREADS), 0, stream,
                           data, indexes, weight, (const unsigned short*)d_ws, bias, out);
    }
}

// Round 8
// 129.387 us; speedup vs baseline: 4.8553x; 4.8553x over previous
//
#include <hip/hip_runtime.h>

#define B_      128
#define C_IN_   256
#define NPTS    1024
#define C_OUT_  256
#define L_      3069
#define NTRIP   1023
#define T_OUT   1024
#define FEATS_SIZE (B_ * C_OUT_ * T_OUT)
#define KTOT    768

#define THREADS 512

typedef __attribute__((ext_vector_type(8))) short           bf16x8;
typedef __attribute__((ext_vector_type(8))) unsigned short  ushort8;
typedef __attribute__((ext_vector_type(4))) unsigned short  ushort4v;
typedef __attribute__((ext_vector_type(4))) float           f32x4;

__device__ __forceinline__ unsigned short f2bf(float f) {
    union { float f; unsigned u; } v; v.f = f;
    unsigned r = (v.u + 0x7FFFu + ((v.u >> 16) & 1u)) >> 16;   // RNE
    return (unsigned short)r;
}

__device__ __forceinline__ void gload16(const void* g, void* l) {
    __builtin_amdgcn_global_load_lds(
        (const __attribute__((address_space(1))) unsigned int*)g,
        (__attribute__((address_space(3))) unsigned int*)l, 16, 0, 0);
}

// ===================== TIER 2 (fast path) =====================
// K = 24 slices of 32 (slice s: tap t = s>>3, channel block cb = s&7).
// Block tile 256x256 (BN=256), 8 waves 4(m) x 2(n), wave tile 64x128.
// A slice image: 256 rows x 64 B (16 KB), slot-XOR (j ^ (r&3)), DOUBLE-buffered.
// B slice image: 256 rows x 64 B (16 KB), same swizzle, TRIPLE-buffered.
// LDS = 2*16 + 3*16 = 80 KB/block.
//
// REGISTER CONTRACT (R7 post-mortem): acc[4][8] = 128 VGPR. launch_bounds
// min-waves/EU MUST be 2 (cap 256), not 4 (cap 128 -> full acc spill to
// scratch: R7 showed FETCH 892MB / WRITE 1.6GB of scratch traffic).
// One 8-wave block/CU; grid 512 = 2 rounds.
//
// Pipeline: body s = wait vmcnt(2) -> s_barrier -> ds_read a[4],bb[0..3] ->
//           issue A(s+1) [2 gload16] + B(s+2) [2 gload16] -> 16 MFMA ->
//           ds_read bb[4..7] -> 16 MFMA.  (bb split halves live pressure.)
// vmcnt(2): queue ... A(s),B(s+1) -> needing A(s),B(s) done leaves only
// B(s+1)'s 2 ops outstanding. Body 23: vmcnt(0).
//
// ws: [0, 393216): wbf4 — weights bf16, slice-major pre-swizzled
//     [393216, +67108864): dataT — bf16 [b][n][c]
#define WOFF_T  0
#define DOFF_T  393216
#define WS_NEED_T2 (393216 + 67108864)

#define NSLICE  24
#define SLBYTES 16384
#define BBASE0  32768                  // B buffers at 32768 + (s%3)*16384
#define IDX6    65536                  // idx overlay in B-buf2 (prologue only)
#define SMEM6   81920
#define BN2     256

#define WAITV(n) asm volatile("s_waitcnt vmcnt(" #n ")" ::: "memory")

// weight fp32 -> bf16, slice-major fragment layout, slot-XOR pre-applied
__global__ __launch_bounds__(256) void convert_w4(
    const float* __restrict__ w, unsigned short* __restrict__ wbf4)
{
    int i = blockIdx.x * 256 + threadIdx.x;          // 0 .. 196607
    if (i >= C_OUT_ * KTOT) return;
    int e  = i & 7;
    int j  = (i >> 3) & 3;
    int r  = (i >> 5) & 255;
    int s  = i >> 13;           // 0..23
    int t  = s >> 3;
    int cb = s & 7;
    int lgp = j ^ (r & 3);
    int c  = cb * 32 + lgp * 8 + e;
    wbf4[i] = f2bf(w[r * KTOT + c * 3 + t]);
}

// data fp32 [b][c][n] -> dataT bf16 [b][n][c]
__global__ __launch_bounds__(256) void transpose_data(
    const float* __restrict__ data, unsigned short* __restrict__ dataT)
{
    __shared__ float T[64][68];
    const int bid = blockIdx.x;
    const int b   = bid >> 6;
    const int ct  = (bid & 63) >> 4;     // 0..3
    const int nt  = bid & 15;            // 0..15
    const int c0  = ct * 64, n0 = nt * 64;
    const int t   = threadIdx.x;
    const int row = t >> 2;              // 0..63
    const int q   = t & 3;

    const float* src = data + ((size_t)(b * C_IN_ + c0 + row)) * NPTS + n0 + q * 16;
    #pragma unroll
    for (int j = 0; j < 4; ++j) {
        float4 v = *(const float4*)(src + j * 4);
        *(float4*)&T[row][q * 16 + j * 4] = v;
    }
    __syncthreads();

    ushort8 o0, o1;
    #pragma unroll
    for (int j = 0; j < 8; ++j)  o0[j] = f2bf(T[q * 16 + j][row]);
    #pragma unroll
    for (int j = 0; j < 8; ++j)  o1[j] = f2bf(T[q * 16 + 8 + j][row]);
    unsigned short* dst = dataT + ((size_t)(b * NPTS) + n0 + row) * C_IN_ + c0 + q * 16;
    *(ushort8*)(dst)     = o0;
    *(ushort8*)(dst + 8) = o1;
}

// 8 waves as 4(m) x 2(n); per-wave output tile 64x128 (mi=4, ni=8).
__global__ __launch_bounds__(THREADS, 2) void treeconv_mfma6(
    const unsigned short* __restrict__ wbf4,
    const unsigned short* __restrict__ dataT,
    const int*   __restrict__ indexes,
    const float* __restrict__ bias,
    float*       __restrict__ out)
{
    __shared__ alignas(16) unsigned char smem[SMEM6];
    int* idx_s = (int*)(smem + IDX6);

    const int tid = threadIdx.x;
    // bijective XCD swizzle (512 = 8 XCD * 64); consecutive wg (same batch's
    // 4 n-tiles) land on the same XCD -> dataT L2 reuse.
    const int wg  = (blockIdx.x & 7) * 64 + (blockIdx.x >> 3);
    const int b   = wg >> 2;
    const int nt0 = (wg & 3) * BN2;

    {
        int off = nt0 * 3 + tid;
        idx_s[tid] = (off < L_) ? indexes[b * L_ + off] : 0;
        if (tid < BN2 * 3 - 512) {
            int off2 = nt0 * 3 + 512 + tid;
            idx_s[512 + tid] = (off2 < L_) ? indexes[b * L_ + off2] : 0;
        }
    }
    __syncthreads();

    const int lane = tid & 63;
    const int wid  = tid >> 6;
    const int wm   = wid >> 1;     // m base = wm*64
    const int wn   = wid & 1;      // n base = wn*128
    const int l15  = lane & 15;
    const int lg   = lane >> 4;

    // ---- B stage gather offsets: 2 slots/thread (tid, tid+512) ----
    // image (n = slot>>2, j = slot&3) holds channels for lgp = j ^ (n&3)
    unsigned bofa[3], bofb[3];
    {
        const int s0 = tid,        n0_ = s0 >> 2, lp0 = (s0 & 3) ^ (n0_ & 3);
        const int s1 = tid + 512,  n1_ = s1 >> 2, lp1 = (s1 & 3) ^ (n1_ & 3);
        #pragma unroll
        for (int t = 0; t < 3; ++t) {
            bofa[t] = (unsigned)(idx_s[n0_ * 3 + t] * 512 + lp0 * 16);
            bofb[t] = (unsigned)(idx_s[n1_ * 3 + t] * 512 + lp1 * 16);
        }
    }

    const char* dTb  = (const char*)dataT + (size_t)b * NPTS * C_IN_ * 2;
    const char* wsrc = (const char*)wbf4;
    const int   a0   = tid * 16;                    // A slot bytes (x2: +8192)
    const int   bd0  = tid * 16;                    // B slot bytes (x2: +8192)

    // fragment read bases (slot-XOR: r&3 == l15&3, lane-constant)
    const unsigned xsl   = (unsigned)((lg ^ (l15 & 3)) << 4);
    const unsigned abase = (unsigned)((wm * 64 + l15) * 64) + xsl;
    const unsigned bbase = (unsigned)(BBASE0 + (wn * 128 + l15) * 64) + xsl;

    f32x4 acc[4][8];
    #pragma unroll
    for (int mi = 0; mi < 4; ++mi)
        #pragma unroll
        for (int ni = 0; ni < 8; ++ni)
            acc[mi][ni] = (f32x4){0.f, 0.f, 0.f, 0.f};

#define ASTAGE(s) do {                                                        \
        gload16(wsrc + (s) * SLBYTES + a0,        smem + ((s) & 1) * SLBYTES + a0); \
        gload16(wsrc + (s) * SLBYTES + a0 + 8192, smem + ((s) & 1) * SLBYTES + a0 + 8192); \
    } while (0)
#define BSTAGE(s) do {                                                        \
        unsigned c_ = (unsigned)(((s) & 7) * 64);                             \
        unsigned b0_ = (((s) >> 3) == 0 ? bofa[0] : ((s) >> 3) == 1 ? bofa[1] : bofa[2]) + c_; \
        unsigned b1_ = (((s) >> 3) == 0 ? bofb[0] : ((s) >> 3) == 1 ? bofb[1] : bofb[2]) + c_; \
        gload16(dTb + b0_, smem + BBASE0 + ((s) % 3) * SLBYTES + bd0);        \
        gload16(dTb + b1_, smem + BBASE0 + ((s) % 3) * SLBYTES + bd0 + 8192); \
    } while (0)

    // prologue queue: A(0) A(0) B(0) B(0) B(1) B(1)
    ASTAGE(0);
    BSTAGE(0);
    BSTAGE(1);

    #pragma unroll
    for (int s = 0; s < NSLICE; ++s) {
        // need A(s),B(s) retired; only B(s+1) (2 ops) may stay in flight.
        if (s == NSLICE - 1) WAITV(0);
        else                 WAITV(2);
        __builtin_amdgcn_s_barrier();
        asm volatile("" ::: "memory");

        const unsigned char* ap = smem + (s & 1) * SLBYTES;
        const unsigned char* bp = smem + (s % 3) * SLBYTES;
        bf16x8 a[4], bb[4];
        #pragma unroll
        for (int mi = 0; mi < 4; ++mi)
            a[mi] = *(const bf16x8*)(ap + abase + mi * 1024);
        #pragma unroll
        for (int ni = 0; ni < 4; ++ni)
            bb[ni] = *(const bf16x8*)(bp + bbase + ni * 1024);

        // issue next stages; targets were freed by the barrier above:
        // A(s+1) -> A-buf (s+1)&1 (read in body s-1); B(s+2) -> B-buf
        // (s+2)%3 == (s-1)%3 (read in body s-1). Writes never touch ap/bp.
        if (s + 1 < NSLICE) ASTAGE(s + 1);
        if (s + 2 < NSLICE) BSTAGE(s + 2);

        // half 1: ni 0..3
        #pragma unroll
        for (int mi = 0; mi < 4; ++mi)
            #pragma unroll
            for (int ni = 0; ni < 4; ++ni)
                acc[mi][ni] = __builtin_amdgcn_mfma_f32_16x16x32_bf16(
                    a[mi], bb[ni], acc[mi][ni], 0, 0, 0);

        // half 2: ni 4..7 (reuse bb regs -> peak live stays ~176)
        #pragma unroll
        for (int ni = 0; ni < 4; ++ni)
            bb[ni] = *(const bf16x8*)(bp + bbase + (ni + 4) * 1024);
        #pragma unroll
        for (int mi = 0; mi < 4; ++mi)
            #pragma unroll
            for (int ni = 0; ni < 4; ++ni)
                acc[mi][ni + 4] = __builtin_amdgcn_mfma_f32_16x16x32_bf16(
                    a[mi], bb[ni], acc[mi][ni + 4], 0, 0, 0);
    }
#undef ASTAGE
#undef BSTAGE

    float* outB = out + (size_t)b * (C_OUT_ * T_OUT);
    #pragma unroll
    for (int mi = 0; mi < 4; ++mi) {
        #pragma unroll
        for (int r = 0; r < 4; ++r) {
            int o = wm * 64 + mi * 16 + lg * 4 + r;
            float bv = bias[o];
            #pragma unroll
            for (int ni = 0; ni < 8; ++ni) {
                int n = nt0 + wn * 128 + ni * 16 + l15;
                if (n < NTRIP)
                    outB[o * T_OUT + 1 + n] = acc[mi][ni][r] + bv;
            }
        }
    }
}

// ===================== TIER 1/0 (round-2 fallback) =====================
#define BN      64
#define BK      96
#define NCHUNK  8
#define AS_OFF  0
#define BS_OFF  49152
#define IDX_OFF 61440
#define SMEM_BYTES 62208

template<bool PREW>
__global__ __launch_bounds__(THREADS, 4) void treeconv_mfma(
    const float* __restrict__ data,
    const int*   __restrict__ indexes,
    const float* __restrict__ w32,
    const unsigned short* __restrict__ wbf,
    const float* __restrict__ bias,
    float*       __restrict__ out)
{
    __shared__ alignas(16) unsigned char smem[SMEM_BYTES];
    int* idx_s = (int*)(smem + IDX_OFF);

    const int tid = threadIdx.x;
    const int b   = blockIdx.x >> 4;
    const int nt0 = (blockIdx.x & 15) * BN;

    if (tid < BN * 3) {
        int off = nt0 * 3 + tid;
        idx_s[tid] = (off < L_) ? indexes[b * L_ + off] : 0;
    }
    __syncthreads();

    const int lane = tid & 63;
    const int wid  = tid >> 6;
    const int wm   = wid >> 1;
    const int wn   = wid & 1;
    const int l15  = lane & 15;
    const int lg   = lane >> 4;

    f32x4 acc[4][2];
    #pragma unroll
    for (int mi = 0; mi < 4; ++mi)
        #pragma unroll
        for (int ni = 0; ni < 2; ++ni)
            acc[mi][ni] = (f32x4){0.f, 0.f, 0.f, 0.f};

    const float* dataB = data + (size_t)b * (C_IN_ * NPTS);
    const int ar = tid >> 1;
    const int ah = tid & 1;
    const int gn = tid & 63;
    const int g8 = tid >> 6;

    for (int kc = 0; kc < NCHUNK; ++kc) {
        {
            const int ab = ar * 192 + ah * 96;
            const int sw = (ar & 7) << 4;
            if (PREW) {
                const ushort8* src = (const ushort8*)(wbf + ar * KTOT + kc * BK + ah * 48);
                #pragma unroll
                for (int j = 0; j < 6; ++j) {
                    ushort8 v = src[j];
                    *(ushort8*)(smem + ((ab + j * 16) ^ sw)) = v;
                }
            } else {
                const float* src = w32 + ar * KTOT + kc * BK + ah * 48;
                #pragma unroll
                for (int j = 0; j < 6; ++j) {
                    float4 fa = *(const float4*)(src + j * 8);
                    float4 fb = *(const float4*)(src + j * 8 + 4);
                    ushort8 v;
                    v[0] = f2bf(fa.x); v[1] = f2bf(fa.y); v[2] = f2bf(fa.z); v[3] = f2bf(fa.w);
                    v[4] = f2bf(fb.x); v[5] = f2bf(fb.y); v[6] = f2bf(fb.z); v[7] = f2bf(fb.w);
                    *(ushort8*)(smem + ((ab + j * 16) ^ sw)) = v;
                }
            }
        }
        {
            const int* ip = idx_s + gn * 3;
            int ix0 = ip[0], ix1 = ip[1], ix2 = ip[2];
            const float* dp = dataB + (kc * 32 + g8 * 4) * NPTS;
            unsigned short vals[12];
            #pragma unroll
            for (int ci = 0; ci < 4; ++ci) {
                vals[ci * 3 + 0] = f2bf(dp[ix0]);
                vals[ci * 3 + 1] = f2bf(dp[ix1]);
                vals[ci * 3 + 2] = f2bf(dp[ix2]);
                dp += NPTS;
            }
            const int bb = BS_OFF + gn * 192 + g8 * 24;
            const int sw = (gn & 7) << 4;
            #pragma unroll
            for (int q = 0; q < 3; ++q) {
                ushort4v v;
                v[0] = vals[q * 4 + 0]; v[1] = vals[q * 4 + 1];
                v[2] = vals[q * 4 + 2]; v[3] = vals[q * 4 + 3];
                *(ushort4v*)(smem + ((bb + q * 8) ^ sw)) = v;
            }
        }
        __syncthreads();

        #pragma unroll
        for (int ks = 0; ks < 3; ++ks) {
            bf16x8 a[4], bf[2];
            const int kb = ks * 64 + lg * 16;
            #pragma unroll
            for (int mi = 0; mi < 4; ++mi) {
                int row = wm * 64 + mi * 16 + l15;
                a[mi] = *(const bf16x8*)(smem + ((row * 192 + kb) ^ ((row & 7) << 4)));
            }
            #pragma unroll
            for (int ni = 0; ni < 2; ++ni) {
                int row = wn * 32 + ni * 16 + l15;
                bf[ni] = *(const bf16x8*)(smem + ((BS_OFF + row * 192 + kb) ^ ((row & 7) << 4)));
            }
            #pragma unroll
            for (int mi = 0; mi < 4; ++mi)
                #pragma unroll
                for (int ni = 0; ni < 2; ++ni)
                    acc[mi][ni] = __builtin_amdgcn_mfma_f32_16x16x32_bf16(
                        a[mi], bf[ni], acc[mi][ni], 0, 0, 0);
        }
        __syncthreads();
    }

    float* outB = out + (size_t)b * (C_OUT_ * T_OUT);
    #pragma unroll
    for (int mi = 0; mi < 4; ++mi) {
        #pragma unroll
        for (int r = 0; r < 4; ++r) {
            int o = wm * 64 + mi * 16 + lg * 4 + r;
            float bv = bias[o];
            #pragma unroll
            for (int ni = 0; ni < 2; ++ni) {
                int n = nt0 + wn * 32 + ni * 16 + l15;
                if (n < NTRIP)
                    outB[o * T_OUT + 1 + n] = acc[mi][ni][r] + bv;
            }
        }
    }
}

__global__ __launch_bounds__(256) void convert_w(
    const float* __restrict__ w, unsigned short* __restrict__ wbf)
{
    int i = (blockIdx.x * 256 + threadIdx.x) * 4;
    if (i < C_OUT_ * KTOT) {
        float4 f = *(const float4*)(w + i);
        ushort4v v;
        v[0] = f2bf(f.x); v[1] = f2bf(f.y); v[2] = f2bf(f.z); v[3] = f2bf(f.w);
        *(ushort4v*)(wbf + i) = v;
    }
}

__global__ __launch_bounds__(256) void aux_kernel(
    const int* __restrict__ indexes, float* __restrict__ out)
{
    int i = blockIdx.x * 256 + threadIdx.x;
    if (i < B_ * L_)
        out[FEATS_SIZE + i] = (float)indexes[i];
    if (i < B_ * C_OUT_)
        out[(size_t)i * T_OUT] = 0.0f;
}

extern "C" void kernel_launch(void* const* d_in, const int* in_sizes, int n_in,
                              void* d_out, int out_size, void* d_ws, size_t ws_size,
                              hipStream_t stream)
{
    const float* data    = (const float*)d_in[0];
    const int*   indexes = (const int*)d_in[1];
    const float* weight  = (const float*)d_in[2];
    const float* bias    = (const float*)d_in[3];
    float* out = (float*)d_out;

    hipLaunchKernelGGL(aux_kernel, dim3((B_ * L_ + 255) / 256), dim3(256), 0, stream,
                       indexes, out);

    if (ws_size >= (size_t)WS_NEED_T2) {
        unsigned short* wbf4  = (unsigned short*)((char*)d_ws + WOFF_T);
        unsigned short* dataT = (unsigned short*)((char*)d_ws + DOFF_T);
        hipLaunchKernelGGL(convert_w4, dim3((C_OUT_ * KTOT + 255) / 256), dim3(256),
                           0, stream, weight, wbf4);
        hipLaunchKernelGGL(transpose_data, dim3(B_ * 64), dim3(256), 0, stream,
                           data, dataT);
        hipLaunchKernelGGL(treeconv_mfma6, dim3(B_ * 4), dim3(THREADS), 0, stream,
                           wbf4, dataT, indexes, bias, out);
    } else if (ws_size >= (size_t)(C_OUT_ * KTOT * 2)) {
        unsigned short* wbf = (unsigned short*)d_ws;
        hipLaunchKernelGGL(convert_w, dim3((C_OUT_ * KTOT / 4 + 255) / 256), dim3(256),
                           0, stream, weight, wbf);
        hipLaunchKernelGGL((treeconv_mfma<true>), dim3(B_ * 16), dim3(THREADS), 0, stream,
                           data, indexes, weight, wbf, bias, out);
    } else {
        hipLaunchKernelGGL((treeconv_mfma<false>), dim3(B_ * 16), dim3(THREADS), 0, stream,
                           data, indexes, weight, (const unsigned short*)d_ws, bias, out);
    }
}

// Round 9
// 120.812 us; speedup vs baseline: 5.2000x; 1.0710x over previous
//
#include <hip/hip_runtime.h>

#define B_      128
#define C_IN_   256
#define NPTS    1024
#define C_OUT_  256
#define L_      3069
#define NTRIP   1023
#define T_OUT   1024
#define FEATS_SIZE (B_ * C_OUT_ * T_OUT)
#define KTOT    768

#define THREADS 512

typedef __attribute__((ext_vector_type(8))) short           bf16x8;
typedef __attribute__((ext_vector_type(8))) unsigned short  ushort8;
typedef __attribute__((ext_vector_type(4))) unsigned short  ushort4v;
typedef __attribute__((ext_vector_type(4))) float           f32x4;

__device__ __forceinline__ unsigned short f2bf(float f) {
    union { float f; unsigned u; } v; v.f = f;
    unsigned r = (v.u + 0x7FFFu + ((v.u >> 16) & 1u)) >> 16;   // RNE
    return (unsigned short)r;
}

__device__ __forceinline__ void gload16(const void* g, void* l) {
    __builtin_amdgcn_global_load_lds(
        (const __attribute__((address_space(1))) unsigned int*)g,
        (__attribute__((address_space(3))) unsigned int*)l, 16, 0, 0);
}

// ===================== TIER 2 (fast path) =====================
// K decomposed into 24 slices of 32: slice s = (tap t = s>>3, channel block
// cb = s&7).  A slice image: 256 rows x 64 B, slot-XOR (j ^ (r&3)).  B slice
// image: 128 rows x 64 B, same swizzle.  All fragment ds_read_b128 are
// perfect 1KB permutations -> conflict-free.  Stages are LINEAR dest
// (global_load_lds); permutation lives in the SOURCE.
//
// OUTPUT ALIGNMENT (R9): block covers output columns t in [nt0, nt0+128)
// directly (not n+1).  Gather column col corresponds to n = nt0-1+col
// (idx triplet offset shifted by -3; clamped for t=0).  Epilogue stores are
// 64-B aligned, full-line covered; t==0 emits the zeros column.  This
// removes the 4-B misalignment that made every store straddle a sector on
// the 134 MB output.
//
// ws: [0, 393216): wbf4 — weights bf16, slice-major pre-swizzled
//     [393216, +67108864): dataT — bf16 [b][n][c]
#define WOFF_T  0
#define DOFF_T  393216
#define WS_NEED_T2 (393216 + 67108864)

#define NSLICE  24
#define ABYTES  16384
#define BBYTES  8192
#define BUFSZ   (ABYTES + BBYTES)      // 24576
#define SMEM4   (3 * BUFSZ)            // 73728 -> 2 blocks/CU
#define IDX4    (2 * BUFSZ)            // idx overlay in buf2 (prologue only)
#define BN2     128

// weight fp32 -> bf16, slice-major fragment layout, slot-XOR pre-applied
__global__ __launch_bounds__(256) void convert_w4(
    const float* __restrict__ w, unsigned short* __restrict__ wbf4)
{
    int i = blockIdx.x * 256 + threadIdx.x;          // 0 .. 196607
    if (i >= C_OUT_ * KTOT) return;
    int e  = i & 7;
    int j  = (i >> 3) & 3;
    int r  = (i >> 5) & 255;
    int s  = i >> 13;           // 0..23
    int t  = s >> 3;
    int cb = s & 7;
    int lgp = j ^ (r & 3);
    int c  = cb * 32 + lgp * 8 + e;
    wbf4[i] = f2bf(w[r * KTOT + c * 3 + t]);
}

// data fp32 [b][c][n] -> dataT bf16 [b][n][c]
__global__ __launch_bounds__(256) void transpose_data(
    const float* __restrict__ data, unsigned short* __restrict__ dataT)
{
    __shared__ float T[64][68];
    const int bid = blockIdx.x;
    const int b   = bid >> 6;
    const int ct  = (bid & 63) >> 4;     // 0..3
    const int nt  = bid & 15;            // 0..15
    const int c0  = ct * 64, n0 = nt * 64;
    const int t   = threadIdx.x;
    const int row = t >> 2;              // 0..63
    const int q   = t & 3;

    const float* src = data + ((size_t)(b * C_IN_ + c0 + row)) * NPTS + n0 + q * 16;
    #pragma unroll
    for (int j = 0; j < 4; ++j) {
        float4 v = *(const float4*)(src + j * 4);
        *(float4*)&T[row][q * 16 + j * 4] = v;
    }
    __syncthreads();

    ushort8 o0, o1;
    #pragma unroll
    for (int j = 0; j < 8; ++j)  o0[j] = f2bf(T[q * 16 + j][row]);
    #pragma unroll
    for (int j = 0; j < 8; ++j)  o1[j] = f2bf(T[q * 16 + 8 + j][row]);
    unsigned short* dst = dataT + ((size_t)(b * NPTS) + n0 + row) * C_IN_ + c0 + q * 16;
    *(ushort8*)(dst)     = o0;
    *(ushort8*)(dst + 8) = o1;
}

// 8 waves as 4(m) x 2(n); per-wave output tile 64x64 (mi=4, ni=4).
// Triple-buffered LDS pipeline, counted vmcnt, raw barriers.
__global__ __launch_bounds__(THREADS, 4) void treeconv_mfma4(
    const unsigned short* __restrict__ wbf4,
    const unsigned short* __restrict__ dataT,
    const int*   __restrict__ indexes,
    const float* __restrict__ bias,
    float*       __restrict__ out)
{
    __shared__ alignas(16) unsigned char smem[SMEM4];
    int* idx_s = (int*)(smem + IDX4);

    const int tid = threadIdx.x;
    // bijective XCD swizzle (1024 = 8 XCD * 128): batch's 8 t-tiles share one XCD L2
    const int wg  = (blockIdx.x & 7) * 128 + (blockIdx.x >> 3);
    const int b   = wg >> 3;
    const int nt0 = (wg & 7) * BN2;      // output column base (t)

    if (tid < BN2 * 3) {
        // triplet for gather column col: n = nt0 - 1 + col
        int off = (nt0 - 1) * 3 + tid;
        idx_s[tid] = (off >= 0 && off < L_) ? indexes[b * L_ + off] : 0;
    }
    __syncthreads();

    const int lane = tid & 63;
    const int wid  = tid >> 6;
    const int wm   = wid >> 1;     // m base = wm*64
    const int wn   = wid & 1;      // t base = wn*64
    const int l15  = lane & 15;
    const int lg   = lane >> 4;

    // ---- B stage gather offsets, one 16B slot per thread ----
    // slot = wid*64+lane; image (col = slot>>2, j = slot&3) holds channels
    // for lgp = j ^ (col&3) of point idx[col*3 + tap].
    const int slotB = wid * 64 + lane;
    const int nB    = slotB >> 2;
    const int lgp   = (slotB & 3) ^ (nB & 3);
    const unsigned boff0 = (unsigned)(idx_s[nB * 3 + 0] * 512 + lgp * 16);
    const unsigned boff1 = (unsigned)(idx_s[nB * 3 + 1] * 512 + lgp * 16);
    const unsigned boff2 = (unsigned)(idx_s[nB * 3 + 2] * 512 + lgp * 16);
    const int bdst = ABYTES + slotB * 16;

    const char* dTb  = (const char*)dataT + (size_t)b * NPTS * C_IN_ * 2;
    const char* wsrc = (const char*)wbf4;
    const int   a0   = (wid * 128 + lane) * 16;     // A stage: 2 slots/thread

    // fragment read bases (slot-XOR: r&3 == l15&3, lane-constant)
    const unsigned xsl   = (unsigned)((lg ^ (l15 & 3)) << 4);
    const unsigned abase = (unsigned)((wm * 64 + l15) * 64) + xsl;
    const unsigned bbase = (unsigned)(ABYTES + (wn * 64 + l15) * 64) + xsl;

    f32x4 acc[4][4];
    #pragma unroll
    for (int mi = 0; mi < 4; ++mi)
        #pragma unroll
        for (int ni = 0; ni < 4; ++ni)
            acc[mi][ni] = (f32x4){0.f, 0.f, 0.f, 0.f};

#define STAGE4(s, buf) do {                                                   \
        gload16(wsrc + (s) * ABYTES + a0,        smem + (buf) * BUFSZ + a0);  \
        gload16(wsrc + (s) * ABYTES + a0 + 1024, smem + (buf) * BUFSZ + a0 + 1024); \
        unsigned bo = (((s) >> 3) == 0 ? boff0 : ((s) >> 3) == 1 ? boff1 : boff2) \
                      + (unsigned)(((s) & 7) * 64);                           \
        gload16(dTb + bo, smem + (buf) * BUFSZ + bdst);                       \
    } while (0)

    // prologue: slices 0,1 in flight (6 loads outstanding)
    STAGE4(0, 0);
    STAGE4(1, 1);

    #pragma unroll
    for (int s = 0; s < NSLICE; ++s) {
        // outstanding: {s, s+1} (6). Wait slice s done, keep s+1 in flight.
        if (s == NSLICE - 1) asm volatile("s_waitcnt vmcnt(0)" ::: "memory");
        else                 asm volatile("s_waitcnt vmcnt(3)" ::: "memory");
        __builtin_amdgcn_s_barrier();
        asm volatile("" ::: "memory");

        const unsigned char* bufp = smem + (s % 3) * BUFSZ;
        bf16x8 a[4], bb[4];
        #pragma unroll
        for (int mi = 0; mi < 4; ++mi)
            a[mi] = *(const bf16x8*)(bufp + abase + mi * 1024);
        #pragma unroll
        for (int ni = 0; ni < 4; ++ni)
            bb[ni] = *(const bf16x8*)(bufp + bbase + ni * 1024);

        // issue stage of slice s+2 (overwrites buf (s+2)%3 == (s-1)%3; all
        // waves are past the barrier, so slice s-1 reads are complete)
        if (s + 2 < NSLICE) STAGE4(s + 2, (s + 2) % 3);

        #pragma unroll
        for (int mi = 0; mi < 4; ++mi)
            #pragma unroll
            for (int ni = 0; ni < 4; ++ni)
                acc[mi][ni] = __builtin_amdgcn_mfma_f32_16x16x32_bf16(
                    a[mi], bb[ni], acc[mi][ni], 0, 0, 0);
    }
#undef STAGE4

    // aligned epilogue: full coverage of t in [nt0, nt0+128); t==0 -> 0.0
    float* outB = out + (size_t)b * (C_OUT_ * T_OUT);
    #pragma unroll
    for (int mi = 0; mi < 4; ++mi) {
        #pragma unroll
        for (int r = 0; r < 4; ++r) {
            int o = wm * 64 + mi * 16 + lg * 4 + r;
            float bv = bias[o];
            #pragma unroll
            for (int ni = 0; ni < 4; ++ni) {
                int t = nt0 + wn * 64 + ni * 16 + l15;
                float v = acc[mi][ni][r] + bv;
                if (t == 0) v = 0.0f;
                outB[o * T_OUT + t] = v;
            }
        }
    }
}

// ===================== TIER 1/0 (round-2 fallback) =====================
#define BN      64
#define BK      96
#define NCHUNK  8
#define AS_OFF  0
#define BS_OFF  49152
#define IDX_OFF 61440
#define SMEM_BYTES 62208

template<bool PREW>
__global__ __launch_bounds__(THREADS, 4) void treeconv_mfma(
    const float* __restrict__ data,
    const int*   __restrict__ indexes,
    const float* __restrict__ w32,
    const unsigned short* __restrict__ wbf,
    const float* __restrict__ bias,
    float*       __restrict__ out)
{
    __shared__ alignas(16) unsigned char smem[SMEM_BYTES];
    int* idx_s = (int*)(smem + IDX_OFF);

    const int tid = threadIdx.x;
    const int b   = blockIdx.x >> 4;
    const int nt0 = (blockIdx.x & 15) * BN;

    if (tid < BN * 3) {
        int off = nt0 * 3 + tid;
        idx_s[tid] = (off < L_) ? indexes[b * L_ + off] : 0;
    }
    __syncthreads();

    const int lane = tid & 63;
    const int wid  = tid >> 6;
    const int wm   = wid >> 1;
    const int wn   = wid & 1;
    const int l15  = lane & 15;
    const int lg   = lane >> 4;

    f32x4 acc[4][2];
    #pragma unroll
    for (int mi = 0; mi < 4; ++mi)
        #pragma unroll
        for (int ni = 0; ni < 2; ++ni)
            acc[mi][ni] = (f32x4){0.f, 0.f, 0.f, 0.f};

    const float* dataB = data + (size_t)b * (C_IN_ * NPTS);
    const int ar = tid >> 1;
    const int ah = tid & 1;
    const int gn = tid & 63;
    const int g8 = tid >> 6;

    for (int kc = 0; kc < NCHUNK; ++kc) {
        {
            const int ab = ar * 192 + ah * 96;
            const int sw = (ar & 7) << 4;
            if (PREW) {
                const ushort8* src = (const ushort8*)(wbf + ar * KTOT + kc * BK + ah * 48);
                #pragma unroll
                for (int j = 0; j < 6; ++j) {
                    ushort8 v = src[j];
                    *(ushort8*)(smem + ((ab + j * 16) ^ sw)) = v;
                }
            } else {
                const float* src = w32 + ar * KTOT + kc * BK + ah * 48;
                #pragma unroll
                for (int j = 0; j < 6; ++j) {
                    float4 fa = *(const float4*)(src + j * 8);
                    float4 fb = *(const float4*)(src + j * 8 + 4);
                    ushort8 v;
                    v[0] = f2bf(fa.x); v[1] = f2bf(fa.y); v[2] = f2bf(fa.z); v[3] = f2bf(fa.w);
                    v[4] = f2bf(fb.x); v[5] = f2bf(fb.y); v[6] = f2bf(fb.z); v[7] = f2bf(fb.w);
                    *(ushort8*)(smem + ((ab + j * 16) ^ sw)) = v;
                }
            }
        }
        {
            const int* ip = idx_s + gn * 3;
            int ix0 = ip[0], ix1 = ip[1], ix2 = ip[2];
            const float* dp = dataB + (kc * 32 + g8 * 4) * NPTS;
            unsigned short vals[12];
            #pragma unroll
            for (int ci = 0; ci < 4; ++ci) {
                vals[ci * 3 + 0] = f2bf(dp[ix0]);
                vals[ci * 3 + 1] = f2bf(dp[ix1]);
                vals[ci * 3 + 2] = f2bf(dp[ix2]);
                dp += NPTS;
            }
            const int bb = BS_OFF + gn * 192 + g8 * 24;
            const int sw = (gn & 7) << 4;
            #pragma unroll
            for (int q = 0; q < 3; ++q) {
                ushort4v v;
                v[0] = vals[q * 4 + 0]; v[1] = vals[q * 4 + 1];
                v[2] = vals[q * 4 + 2]; v[3] = vals[q * 4 + 3];
                *(ushort4v*)(smem + ((bb + q * 8) ^ sw)) = v;
            }
        }
        __syncthreads();

        #pragma unroll
        for (int ks = 0; ks < 3; ++ks) {
            bf16x8 a[4], bf[2];
            const int kb = ks * 64 + lg * 16;
            #pragma unroll
            for (int mi = 0; mi < 4; ++mi) {
                int row = wm * 64 + mi * 16 + l15;
                a[mi] = *(const bf16x8*)(smem + ((row * 192 + kb) ^ ((row & 7) << 4)));
            }
            #pragma unroll
            for (int ni = 0; ni < 2; ++ni) {
                int row = wn * 32 + ni * 16 + l15;
                bf[ni] = *(const bf16x8*)(smem + ((BS_OFF + row * 192 + kb) ^ ((row & 7) << 4)));
            }
            #pragma unroll
            for (int mi = 0; mi < 4; ++mi)
                #pragma unroll
                for (int ni = 0; ni < 2; ++ni)
                    acc[mi][ni] = __builtin_amdgcn_mfma_f32_16x16x32_bf16(
                        a[mi], bf[ni], acc[mi][ni], 0, 0, 0);
        }
        __syncthreads();
    }

    float* outB = out + (size_t)b * (C_OUT_ * T_OUT);
    #pragma unroll
    for (int mi = 0; mi < 4; ++mi) {
        #pragma unroll
        for (int r = 0; r < 4; ++r) {
            int o = wm * 64 + mi * 16 + lg * 4 + r;
            float bv = bias[o];
            #pragma unroll
            for (int ni = 0; ni < 2; ++ni) {
                int n = nt0 + wn * 32 + ni * 16 + l15;
                if (n < NTRIP)
                    outB[o * T_OUT + 1 + n] = acc[mi][ni][r] + bv;
            }
        }
    }
}

__global__ __launch_bounds__(256) void convert_w(
    const float* __restrict__ w, unsigned short* __restrict__ wbf)
{
    int i = (blockIdx.x * 256 + threadIdx.x) * 4;
    if (i < C_OUT_ * KTOT) {
        float4 f = *(const float4*)(w + i);
        ushort4v v;
        v[0] = f2bf(f.x); v[1] = f2bf(f.y); v[2] = f2bf(f.z); v[3] = f2bf(f.w);
        *(ushort4v*)(wbf + i) = v;
    }
}

__global__ __launch_bounds__(256) void aux_kernel(
    const int* __restrict__ indexes, float* __restrict__ out)
{
    int i = blockIdx.x * 256 + threadIdx.x;
    if (i < B_ * L_)
        out[FEATS_SIZE + i] = (float)indexes[i];
    if (i < B_ * C_OUT_)
        out[(size_t)i * T_OUT] = 0.0f;
}

extern "C" void kernel_launch(void* const* d_in, const int* in_sizes, int n_in,
                              void* d_out, int out_size, void* d_ws, size_t ws_size,
                              hipStream_t stream)
{
    const float* data    = (const float*)d_in[0];
    const int*   indexes = (const int*)d_in[1];
    const float* weight  = (const float*)d_in[2];
    const float* bias    = (const float*)d_in[3];
    float* out = (float*)d_out;

    hipLaunchKernelGGL(aux_kernel, dim3((B_ * L_ + 255) / 256), dim3(256), 0, stream,
                       indexes, out);

    if (ws_size >= (size_t)WS_NEED_T2) {
        unsigned short* wbf4  = (unsigned short*)((char*)d_ws + WOFF_T);
        unsigned short* dataT = (unsigned short*)((char*)d_ws + DOFF_T);
        hipLaunchKernelGGL(convert_w4, dim3((C_OUT_ * KTOT + 255) / 256), dim3(256),
                           0, stream, weight, wbf4);
        hipLaunchKernelGGL(transpose_data, dim3(B_ * 64), dim3(256), 0, stream,
                           data, dataT);
        hipLaunchKernelGGL(treeconv_mfma4, dim3(B_ * 8), dim3(THREADS), 0, stream,
                           wbf4, dataT, indexes, bias, out);
    } else if (ws_size >= (size_t)(C_OUT_ * KTOT * 2)) {
        unsigned short* wbf = (unsigned short*)d_ws;
        hipLaunchKernelGGL(convert_w, dim3((C_OUT_ * KTOT / 4 + 255) / 256), dim3(256),
                           0, stream, weight, wbf);
        hipLaunchKernelGGL((treeconv_mfma<true>), dim3(B_ * 16), dim3(THREADS), 0, stream,
                           data, indexes, weight, wbf, bias, out);
    } else {
        hipLaunchKernelGGL((treeconv_mfma<false>), dim3(B_ * 16), dim3(THREADS), 0, stream,
                           data, indexes, weight, (const unsigned short*)d_ws, bias, out);
    }
}

// Round 10
// 116.388 us; speedup vs baseline: 5.3976x; 1.0380x over previous
//
#include <hip/hip_runtime.h>

#define B_      128
#define C_IN_   256
#define NPTS    1024
#define C_OUT_  256
#define L_      3069
#define NTRIP   1023
#define T_OUT   1024
#define FEATS_SIZE (B_ * C_OUT_ * T_OUT)
#define KTOT    768

#define THREADS 512

typedef __attribute__((ext_vector_type(8))) short           bf16x8;
typedef __attribute__((ext_vector_type(8))) unsigned short  ushort8;
typedef __attribute__((ext_vector_type(4))) unsigned short  ushort4v;
typedef __attribute__((ext_vector_type(4))) float           f32x4;

__device__ __forceinline__ unsigned short f2bf(float f) {
    union { float f; unsigned u; } v; v.f = f;
    unsigned r = (v.u + 0x7FFFu + ((v.u >> 16) & 1u)) >> 16;   // RNE
    return (unsigned short)r;
}

__device__ __forceinline__ void gload16(const void* g, void* l) {
    __builtin_amdgcn_global_load_lds(
        (const __attribute__((address_space(1))) unsigned int*)g,
        (__attribute__((address_space(3))) unsigned int*)l, 16, 0, 0);
}

// ===================== TIER 2 (fast path) =====================
// K decomposed into 24 slices of 32: slice s = (tap t = s>>3, channel block
// cb = s&7, channels cb*32..+31).  A slice image: 256 rows x 64 B, slot-XOR
// swizzled: row r, 16B-slot j holds channels for lg = j ^ (r&3).  B slice
// image: 128 rows x 64 B, same swizzle.  All fragment ds_read_b128 are
// perfect 1KB permutations -> conflict-free.  Stages are LINEAR dest
// (global_load_lds); the permutation lives in the SOURCE (convert_w4 for A,
// per-slot gather offset for B).
//
// STRUCTURAL CONSTANTS (locked by 9 rounds of probing):
//  - 128 regs/wave (64 acc AGPR + 64 VGPR) x 16 waves = full 2048 pool ->
//    2 blocks/CU exactly; ANY extra register drops a wave (R5/R7/R8).
//  - 3-deep pipeline = LDS budget (73728 x 2 = 147456 <= 160K).
//  - counted vmcnt(3): slice s+1 stays in flight across the barrier (R3).
//  - setprio: null (R6).  BN=256: worse (R8).  A-from-global: worse (R5).
//    Aligned/shifted stores: worse (R9).
//
// ws: [0, 393216): wbf4 — weights bf16, slice-major pre-swizzled
//     [393216, +67108864): dataT — bf16 [b][n][c]
#define WOFF_T  0
#define DOFF_T  393216
#define WS_NEED_T2 (393216 + 67108864)

#define NSLICE  24
#define ABYTES  16384
#define BBYTES  8192
#define BUFSZ   (ABYTES + BBYTES)      // 24576
#define SMEM4   (3 * BUFSZ)            // 73728
#define IDX4    (2 * BUFSZ)            // idx overlay in buf2 (prologue only)
#define BN2     128

// weight fp32 -> bf16, slice-major fragment layout, slot-XOR pre-applied
__global__ __launch_bounds__(256) void convert_w4(
    const float* __restrict__ w, unsigned short* __restrict__ wbf4)
{
    int i = blockIdx.x * 256 + threadIdx.x;          // 0 .. 196607
    if (i >= C_OUT_ * KTOT) return;
    int e  = i & 7;
    int j  = (i >> 3) & 3;
    int r  = (i >> 5) & 255;
    int s  = i >> 13;           // 0..23
    int t  = s >> 3;
    int cb = s & 7;
    int lgp = j ^ (r & 3);
    int c  = cb * 32 + lgp * 8 + e;
    wbf4[i] = f2bf(w[r * KTOT + c * 3 + t]);
}

// data fp32 [b][c][n] -> dataT bf16 [b][n][c]
__global__ __launch_bounds__(256) void transpose_data(
    const float* __restrict__ data, unsigned short* __restrict__ dataT)
{
    __shared__ float T[64][68];
    const int bid = blockIdx.x;
    const int b   = bid >> 6;
    const int ct  = (bid & 63) >> 4;     // 0..3
    const int nt  = bid & 15;            // 0..15
    const int c0  = ct * 64, n0 = nt * 64;
    const int t   = threadIdx.x;
    const int row = t >> 2;              // 0..63
    const int q   = t & 3;

    const float* src = data + ((size_t)(b * C_IN_ + c0 + row)) * NPTS + n0 + q * 16;
    #pragma unroll
    for (int j = 0; j < 4; ++j) {
        float4 v = *(const float4*)(src + j * 4);
        *(float4*)&T[row][q * 16 + j * 4] = v;
    }
    __syncthreads();

    ushort8 o0, o1;
    #pragma unroll
    for (int j = 0; j < 8; ++j)  o0[j] = f2bf(T[q * 16 + j][row]);
    #pragma unroll
    for (int j = 0; j < 8; ++j)  o1[j] = f2bf(T[q * 16 + 8 + j][row]);
    unsigned short* dst = dataT + ((size_t)(b * NPTS) + n0 + row) * C_IN_ + c0 + q * 16;
    *(ushort8*)(dst)     = o0;
    *(ushort8*)(dst + 8) = o1;
}

// 8 waves as 4(m) x 2(n); per-wave output tile 64x64 (mi=4, ni=4).
// Triple-buffered LDS pipeline, counted vmcnt, raw barriers.
// R10: STAGE issued immediately after the barrier, BEFORE fragment ds_reads
// (gather enters the memory queue earlier; zero register cost).
__global__ __launch_bounds__(THREADS, 4) void treeconv_mfma4(
    const unsigned short* __restrict__ wbf4,
    const unsigned short* __restrict__ dataT,
    const int*   __restrict__ indexes,
    const float* __restrict__ bias,
    float*       __restrict__ out)
{
    __shared__ alignas(16) unsigned char smem[SMEM4];
    int* idx_s = (int*)(smem + IDX4);

    const int tid = threadIdx.x;
    // bijective XCD swizzle (1024 = 8 XCD * 128): batch's 8 n-tiles share one XCD L2
    const int wg  = (blockIdx.x & 7) * 128 + (blockIdx.x >> 3);
    const int b   = wg >> 3;
    const int nt0 = (wg & 7) * BN2;

    if (tid < BN2 * 3) {
        int off = nt0 * 3 + tid;
        idx_s[tid] = (off < L_) ? indexes[b * L_ + off] : 0;
    }
    __syncthreads();

    const int lane = tid & 63;
    const int wid  = tid >> 6;
    const int wm   = wid >> 1;     // m base = wm*64
    const int wn   = wid & 1;      // n base = wn*64
    const int l15  = lane & 15;
    const int lg   = lane >> 4;

    // ---- B stage gather offsets, one 16B slot per thread ----
    // slot = wid*64+lane; image (n = slot>>2, j = slot&3) holds channels for
    // lgp = j ^ (n&3) of point ix[n*3 + tap].
    const int slotB = wid * 64 + lane;
    const int nB    = slotB >> 2;
    const int lgp   = (slotB & 3) ^ (nB & 3);
    const unsigned boff0 = (unsigned)(idx_s[nB * 3 + 0] * 512 + lgp * 16);
    const unsigned boff1 = (unsigned)(idx_s[nB * 3 + 1] * 512 + lgp * 16);
    const unsigned boff2 = (unsigned)(idx_s[nB * 3 + 2] * 512 + lgp * 16);
    const int bdst = ABYTES + slotB * 16;

    const char* dTb  = (const char*)dataT + (size_t)b * NPTS * C_IN_ * 2;
    const char* wsrc = (const char*)wbf4;
    const int   a0   = (wid * 128 + lane) * 16;     // A stage: 2 slots/thread

    // fragment read bases (slot-XOR: r&3 == l15&3, lane-constant)
    const unsigned xsl   = (unsigned)((lg ^ (l15 & 3)) << 4);
    const unsigned abase = (unsigned)((wm * 64 + l15) * 64) + xsl;
    const unsigned bbase = (unsigned)(ABYTES + (wn * 64 + l15) * 64) + xsl;

    f32x4 acc[4][4];
    #pragma unroll
    for (int mi = 0; mi < 4; ++mi)
        #pragma unroll
        for (int ni = 0; ni < 4; ++ni)
            acc[mi][ni] = (f32x4){0.f, 0.f, 0.f, 0.f};

#define STAGE4(s, buf) do {                                                   \
        gload16(wsrc + (s) * ABYTES + a0,        smem + (buf) * BUFSZ + a0);  \
        gload16(wsrc + (s) * ABYTES + a0 + 1024, smem + (buf) * BUFSZ + a0 + 1024); \
        unsigned bo = (((s) >> 3) == 0 ? boff0 : ((s) >> 3) == 1 ? boff1 : boff2) \
                      + (unsigned)(((s) & 7) * 64);                           \
        gload16(dTb + bo, smem + (buf) * BUFSZ + bdst);                       \
    } while (0)

    // prologue: slices 0,1 in flight (6 loads outstanding)
    STAGE4(0, 0);
    STAGE4(1, 1);

    #pragma unroll
    for (int s = 0; s < NSLICE; ++s) {
        // outstanding: {s, s+1} (6). Wait slice s done, keep s+1 in flight.
        if (s == NSLICE - 1) asm volatile("s_waitcnt vmcnt(0)" ::: "memory");
        else                 asm volatile("s_waitcnt vmcnt(3)" ::: "memory");
        __builtin_amdgcn_s_barrier();
        asm volatile("" ::: "memory");

        // issue stage of slice s+2 FIRST (overwrites buf (s+2)%3 == (s-1)%3;
        // all waves are past the barrier, so slice s-1 reads are complete).
        // Issuing before the ds_reads puts the scattered gather into the
        // memory queue ~1 frag-read phase earlier each body.
        if (s + 2 < NSLICE) STAGE4(s + 2, (s + 2) % 3);

        const unsigned char* bufp = smem + (s % 3) * BUFSZ;
        bf16x8 a[4], bb[4];
        #pragma unroll
        for (int mi = 0; mi < 4; ++mi)
            a[mi] = *(const bf16x8*)(bufp + abase + mi * 1024);
        #pragma unroll
        for (int ni = 0; ni < 4; ++ni)
            bb[ni] = *(const bf16x8*)(bufp + bbase + ni * 1024);

        #pragma unroll
        for (int mi = 0; mi < 4; ++mi)
            #pragma unroll
            for (int ni = 0; ni < 4; ++ni)
                acc[mi][ni] = __builtin_amdgcn_mfma_f32_16x16x32_bf16(
                    a[mi], bb[ni], acc[mi][ni], 0, 0, 0);
    }
#undef STAGE4

    float* outB = out + (size_t)b * (C_OUT_ * T_OUT);
    #pragma unroll
    for (int mi = 0; mi < 4; ++mi) {
        #pragma unroll
        for (int r = 0; r < 4; ++r) {
            int o = wm * 64 + mi * 16 + lg * 4 + r;
            float bv = bias[o];
            #pragma unroll
            for (int ni = 0; ni < 4; ++ni) {
                int n = nt0 + wn * 64 + ni * 16 + l15;
                if (n < NTRIP)
                    outB[o * T_OUT + 1 + n] = acc[mi][ni][r] + bv;
            }
        }
    }
}

// ===================== TIER 1/0 (round-2 fallback) =====================
#define BN      64
#define BK      96
#define NCHUNK  8
#define AS_OFF  0
#define BS_OFF  49152
#define IDX_OFF 61440
#define SMEM_BYTES 62208

template<bool PREW>
__global__ __launch_bounds__(THREADS, 4) void treeconv_mfma(
    const float* __restrict__ data,
    const int*   __restrict__ indexes,
    const float* __restrict__ w32,
    const unsigned short* __restrict__ wbf,
    const float* __restrict__ bias,
    float*       __restrict__ out)
{
    __shared__ alignas(16) unsigned char smem[SMEM_BYTES];
    int* idx_s = (int*)(smem + IDX_OFF);

    const int tid = threadIdx.x;
    const int b   = blockIdx.x >> 4;
    const int nt0 = (blockIdx.x & 15) * BN;

    if (tid < BN * 3) {
        int off = nt0 * 3 + tid;
        idx_s[tid] = (off < L_) ? indexes[b * L_ + off] : 0;
    }
    __syncthreads();

    const int lane = tid & 63;
    const int wid  = tid >> 6;
    const int wm   = wid >> 1;
    const int wn   = wid & 1;
    const int l15  = lane & 15;
    const int lg   = lane >> 4;

    f32x4 acc[4][2];
    #pragma unroll
    for (int mi = 0; mi < 4; ++mi)
        #pragma unroll
        for (int ni = 0; ni < 2; ++ni)
            acc[mi][ni] = (f32x4){0.f, 0.f, 0.f, 0.f};

    const float* dataB = data + (size_t)b * (C_IN_ * NPTS);
    const int ar = tid >> 1;
    const int ah = tid & 1;
    const int gn = tid & 63;
    const int g8 = tid >> 6;

    for (int kc = 0; kc < NCHUNK; ++kc) {
        {
            const int ab = ar * 192 + ah * 96;
            const int sw = (ar & 7) << 4;
            if (PREW) {
                const ushort8* src = (const ushort8*)(wbf + ar * KTOT + kc * BK + ah * 48);
                #pragma unroll
                for (int j = 0; j < 6; ++j) {
                    ushort8 v = src[j];
                    *(ushort8*)(smem + ((ab + j * 16) ^ sw)) = v;
                }
            } else {
                const float* src = w32 + ar * KTOT + kc * BK + ah * 48;
                #pragma unroll
                for (int j = 0; j < 6; ++j) {
                    float4 fa = *(const float4*)(src + j * 8);
                    float4 fb = *(const float4*)(src + j * 8 + 4);
                    ushort8 v;
                    v[0] = f2bf(fa.x); v[1] = f2bf(fa.y); v[2] = f2bf(fa.z); v[3] = f2bf(fa.w);
                    v[4] = f2bf(fb.x); v[5] = f2bf(fb.y); v[6] = f2bf(fb.z); v[7] = f2bf(fb.w);
                    *(ushort8*)(smem + ((ab + j * 16) ^ sw)) = v;
                }
            }
        }
        {
            const int* ip = idx_s + gn * 3;
            int ix0 = ip[0], ix1 = ip[1], ix2 = ip[2];
            const float* dp = dataB + (kc * 32 + g8 * 4) * NPTS;
            unsigned short vals[12];
            #pragma unroll
            for (int ci = 0; ci < 4; ++ci) {
                vals[ci * 3 + 0] = f2bf(dp[ix0]);
                vals[ci * 3 + 1] = f2bf(dp[ix1]);
                vals[ci * 3 + 2] = f2bf(dp[ix2]);
                dp += NPTS;
            }
            const int bb = BS_OFF + gn * 192 + g8 * 24;
            const int sw = (gn & 7) << 4;
            #pragma unroll
            for (int q = 0; q < 3; ++q) {
                ushort4v v;
                v[0] = vals[q * 4 + 0]; v[1] = vals[q * 4 + 1];
                v[2] = vals[q * 4 + 2]; v[3] = vals[q * 4 + 3];
                *(ushort4v*)(smem + ((bb + q * 8) ^ sw)) = v;
            }
        }
        __syncthreads();

        #pragma unroll
        for (int ks = 0; ks < 3; ++ks) {
            bf16x8 a[4], bf[2];
            const int kb = ks * 64 + lg * 16;
            #pragma unroll
            for (int mi = 0; mi < 4; ++mi) {
                int row = wm * 64 + mi * 16 + l15;
                a[mi] = *(const bf16x8*)(smem + ((row * 192 + kb) ^ ((row & 7) << 4)));
            }
            #pragma unroll
            for (int ni = 0; ni < 2; ++ni) {
                int row = wn * 32 + ni * 16 + l15;
                bf[ni] = *(const bf16x8*)(smem + ((BS_OFF + row * 192 + kb) ^ ((row & 7) << 4)));
            }
            #pragma unroll
            for (int mi = 0; mi < 4; ++mi)
                #pragma unroll
                for (int ni = 0; ni < 2; ++ni)
                    acc[mi][ni] = __builtin_amdgcn_mfma_f32_16x16x32_bf16(
                        a[mi], bf[ni], acc[mi][ni], 0, 0, 0);
        }
        __syncthreads();
    }

    float* outB = out + (size_t)b * (C_OUT_ * T_OUT);
    #pragma unroll
    for (int mi = 0; mi < 4; ++mi) {
        #pragma unroll
        for (int r = 0; r < 4; ++r) {
            int o = wm * 64 + mi * 16 + lg * 4 + r;
            float bv = bias[o];
            #pragma unroll
            for (int ni = 0; ni < 2; ++ni) {
                int n = nt0 + wn * 32 + ni * 16 + l15;
                if (n < NTRIP)
                    outB[o * T_OUT + 1 + n] = acc[mi][ni][r] + bv;
            }
        }
    }
}

__global__ __launch_bounds__(256) void convert_w(
    const float* __restrict__ w, unsigned short* __restrict__ wbf)
{
    int i = (blockIdx.x * 256 + threadIdx.x) * 4;
    if (i < C_OUT_ * KTOT) {
        float4 f = *(const float4*)(w + i);
        ushort4v v;
        v[0] = f2bf(f.x); v[1] = f2bf(f.y); v[2] = f2bf(f.z); v[3] = f2bf(f.w);
        *(ushort4v*)(wbf + i) = v;
    }
}

__global__ __launch_bounds__(256) void aux_kernel(
    const int* __restrict__ indexes, float* __restrict__ out)
{
    int i = blockIdx.x * 256 + threadIdx.x;
    if (i < B_ * L_)
        out[FEATS_SIZE + i] = (float)indexes[i];
    if (i < B_ * C_OUT_)
        out[(size_t)i * T_OUT] = 0.0f;
}

extern "C" void kernel_launch(void* const* d_in, const int* in_sizes, int n_in,
                              void* d_out, int out_size, void* d_ws, size_t ws_size,
                              hipStream_t stream)
{
    const float* data    = (const float*)d_in[0];
    const int*   indexes = (const int*)d_in[1];
    const float* weight  = (const float*)d_in[2];
    const float* bias    = (const float*)d_in[3];
    float* out = (float*)d_out;

    hipLaunchKernelGGL(aux_kernel, dim3((B_ * L_ + 255) / 256), dim3(256), 0, stream,
                       indexes, out);

    if (ws_size >= (size_t)WS_NEED_T2) {
        unsigned short* wbf4  = (unsigned short*)((char*)d_ws + WOFF_T);
        unsigned short* dataT = (unsigned short*)((char*)d_ws + DOFF_T);
        hipLaunchKernelGGL(convert_w4, dim3((C_OUT_ * KTOT + 255) / 256), dim3(256),
                           0, stream, weight, wbf4);
        hipLaunchKernelGGL(transpose_data, dim3(B_ * 64), dim3(256), 0, stream,
                           data, dataT);
        hipLaunchKernelGGL(treeconv_mfma4, dim3(B_ * 8), dim3(THREADS), 0, stream,
                           wbf4, dataT, indexes, bias, out);
    } else if (ws_size >= (size_t)(C_OUT_ * KTOT * 2)) {
        unsigned short* wbf = (unsigned short*)d_ws;
        hipLaunchKernelGGL(convert_w, dim3((C_OUT_ * KTOT / 4 + 255) / 256), dim3(256),
                           0, stream, weight, wbf);
        hipLaunchKernelGGL((treeconv_mfma<true>), dim3(B_ * 16), dim3(THREADS), 0, stream,
                           data, indexes, weight, wbf, bias, out);
    } else {
        hipLaunchKernelGGL((treeconv_mfma<false>), dim3(B_ * 16), dim3(THREADS), 0, stream,
                           data, indexes, weight, (const unsigned short*)d_ws, bias, out);
    }
}